// Round 8
// baseline (838.541 us; speedup 1.0000x reference)
//
#include <hip/hip_runtime.h>

typedef _Float16 half8_t __attribute__((ext_vector_type(8)));
typedef _Float16 half4_t __attribute__((ext_vector_type(4)));
typedef float f32x4 __attribute__((ext_vector_type(4)));

#define MFMA16(a, b, c) __builtin_amdgcn_mfma_f32_16x16x32_f16((a), (b), (c), 0, 0, 0)

typedef const unsigned int __attribute__((address_space(1)))* gas_ptr;
typedef unsigned int __attribute__((address_space(3)))* las_ptr;

__device__ __forceinline__ void gload16(const void* g, void* l) {
    __builtin_amdgcn_global_load_lds((gas_ptr)g, (las_ptr)l, 16, 0, 0);
}

// m204 bijective XCD swizzle: contiguous wgid chunk per XCD (works for nwg % 8 != 0)
__device__ __forceinline__ int xcd_swizzle(int bid, int nwg) {
    int xcd = bid & 7, i = bid >> 3;
    int q = nwg >> 3, r = nwg & 7;
    return (xcd < r ? xcd * (q + 1) : r * (q + 1) + (xcd - r) * q) + i;
}

// ---------------- convert / transpose ----------------

__global__ void cvt_f2h_kernel(const float* __restrict__ in, _Float16* __restrict__ out, int n4) {
    int stride = gridDim.x * blockDim.x;
    for (int i = blockIdx.x * blockDim.x + threadIdx.x; i < n4; i += stride) {
        f32x4 v = *(const f32x4*)(in + (size_t)4 * i);
        half4_t h;
        h[0] = (_Float16)v[0]; h[1] = (_Float16)v[1];
        h[2] = (_Float16)v[2]; h[3] = (_Float16)v[3];
        *(half4_t*)(out + (size_t)4 * i) = h;
    }
}

// out[j][k] = in[k][j], K fixed at 768
__global__ void transpose768_kernel(const float* __restrict__ in, _Float16* __restrict__ out, int ncols) {
    int idx = blockIdx.x * 256 + threadIdx.x;
    int total = ncols * 768;
    if (idx < total) {
        int j = idx / 768;
        int k = idx - j * 768;
        out[idx] = (_Float16)in[(size_t)k * ncols + j];
    }
}

// ---------------- GEMM core: 128x256 tile, BK=32, 8 waves, 2 blocks/CU ----------------
// A: [M][768] f16 (K contiguous); Bt: [Nout][768] f16 (K contiguous)
// LDS per slot: A [128][32] (8 KiB) + B [256][32] (16 KiB) = 24 KiB; 2 slots = 48 KiB
// -> 2 blocks/CU (with VGPR<=128 via __launch_bounds__(512,4)); co-resident block
// covers the per-tile vmcnt(0) drain (m114 implicit overlap, m97-structure).
// Swizzle (rule #21, verified 0-conflict in R7): LDS[r][slot s] = G[r][s ^ ((r>>1)&3)]
// staged via pre-swizzled global k-offset ((tid&3)^((tid>>3)&3))*8; read slot l4^((l15>>1)&3).
// Loop (R2/R4-proven sync class): STAGE(next) ; ds_read frags ; 16 MFMA ; __syncthreads().

#define STG(buf, kof)                                                             \
    {                                                                             \
        _Float16* Ad = lds + (buf) * 12288 + wave * 512;                          \
        _Float16* Bd = lds + (buf) * 12288 + 4096 + wave * 512;                   \
        gload16(Arow + (kof), Ad);                                                \
        gload16(Brow + (kof), Bd);                                                \
        gload16(Brow + (kof) + 98304, Bd + 4096);                                 \
    }

__device__ __forceinline__ void run_gemm128x256(const _Float16* __restrict__ A,
                                                const _Float16* __restrict__ Bt,
                                                int mbase, int nbase,
                                                _Float16* lds,          // 24576 f16
                                                f32x4 (&acc)[4][4]) {
    const int tid = threadIdx.x;
    const int lane = tid & 63;
    const int wave = tid >> 6;
    const int wr = wave >> 2;        // 0..1  (M half, 64 rows)
    const int wc = wave & 3;         // 0..3  (N quarter, 64 cols)
    const int l15 = lane & 15;
    const int l4 = lane >> 4;
    const int rsw = ((l4 ^ ((l15 >> 1) & 3)) << 3);             // read k-slot offset
    const int ksw = (((tid & 3) ^ ((tid >> 3) & 3)) << 3);      // staging source pre-swizzle

    #pragma unroll
    for (int mi = 0; mi < 4; ++mi)
        #pragma unroll
        for (int ni = 0; ni < 4; ++ni)
            acc[mi][ni] = (f32x4){0.f, 0.f, 0.f, 0.f};

    const _Float16* Arow = A + (size_t)(mbase + (tid >> 2)) * 768 + ksw;   // rows 0..127
    const _Float16* Brow = Bt + (size_t)(nbase + (tid >> 2)) * 768 + ksw;  // rows 0..127 (+128 in STG)

    STG(0, 0)
    __syncthreads();

    #pragma unroll 2
    for (int kt = 0; kt < 24; ++kt) {
        const int buf = kt & 1;
        if (kt < 23) STG(buf ^ 1, (kt + 1) * 32)

        const _Float16* Ac = lds + buf * 12288;
        const _Float16* Bc = Ac + 4096;
        half8_t a[4], b[4];
        #pragma unroll
        for (int mi = 0; mi < 4; ++mi)
            a[mi] = *(const half8_t*)(Ac + (wr * 64 + mi * 16 + l15) * 32 + rsw);
        #pragma unroll
        for (int ni = 0; ni < 4; ++ni)
            b[ni] = *(const half8_t*)(Bc + (wc * 64 + ni * 16 + l15) * 32 + rsw);
        #pragma unroll
        for (int mi = 0; mi < 4; ++mi)
            #pragma unroll
            for (int ni = 0; ni < 4; ++ni)
                acc[mi][ni] = MFMA16(a[mi], b[ni], acc[mi][ni]);
        __syncthreads();
    }
}

// GEMM1: qkv = x @ w_qkv, epilogue: +pos_enc (k), relu (q,k), scatter to head layout
__global__ __launch_bounds__(512, 4) void gemm_qkv_kernel(
    const _Float16* __restrict__ xh, const _Float16* __restrict__ wqkvT,
    const float* __restrict__ pos_enc,
    _Float16* __restrict__ qh, _Float16* __restrict__ kh, _Float16* __restrict__ vh) {
    __shared__ _Float16 lds[24576];
    // XCD-grouped: 9 consecutive wgids (one mtile's ntiles) on one XCD -> A panel L2-shared
    int wgid = xcd_swizzle(blockIdx.x, 392 * 9);
    int mtile = wgid / 9, ntile = wgid - mtile * 9;
    f32x4 acc[4][4];
    run_gemm128x256(xh, wqkvT, mtile * 128, ntile * 256, lds, acc);

    const int tid = threadIdx.x;
    const int lane = tid & 63;
    const int wave = tid >> 6;
    const int wr = wave >> 2;
    const int wc = wave & 3;
    const int l15 = lane & 15;
    const int l4 = lane >> 4;

    // 768 = 3*256: all 256 columns of this block live in one q/k/v segment
    const int s = ntile / 3;
    const int cb = (ntile - s * 3) * 256 + wc * 64;
    _Float16* dst = (s == 0) ? qh : ((s == 1) ? kh : vh);

    #pragma unroll
    for (int mi = 0; mi < 4; ++mi) {
        #pragma unroll
        for (int ni = 0; ni < 4; ++ni) {
            int c = cb + ni * 16 + l15;
            int h = c >> 6, d = c & 63;
            #pragma unroll
            for (int r = 0; r < 4; ++r) {
                int gr = mtile * 128 + wr * 64 + mi * 16 + l4 * 4 + r;
                int b = gr / 196;
                int n = gr - b * 196;
                float v = acc[mi][ni][r];
                if (s == 1) v += pos_enc[n * 768 + c];
                if (s < 2) v = fmaxf(v, 0.f);
                dst[((size_t)(b * 12 + h) * 196 + n) * 64 + d] = (_Float16)v;
            }
        }
    }
}

// GEMM2: out = fused @ w_proj + b_proj (f32 out)
__global__ __launch_bounds__(512, 4) void gemm_proj_kernel(
    const _Float16* __restrict__ fused, const _Float16* __restrict__ wprojT,
    const float* __restrict__ b_proj, float* __restrict__ out) {
    __shared__ _Float16 lds[24576];
    int wgid = xcd_swizzle(blockIdx.x, 392 * 3);
    int mtile = wgid / 3, ntile = wgid - mtile * 3;
    f32x4 acc[4][4];
    run_gemm128x256(fused, wprojT, mtile * 128, ntile * 256, lds, acc);

    const int tid = threadIdx.x;
    const int lane = tid & 63;
    const int wave = tid >> 6;
    const int wr = wave >> 2;
    const int wc = wave & 3;
    const int l15 = lane & 15;
    const int l4 = lane >> 4;

    #pragma unroll
    for (int mi = 0; mi < 4; ++mi) {
        #pragma unroll
        for (int ni = 0; ni < 4; ++ni) {
            int gc = ntile * 256 + wc * 64 + ni * 16 + l15;
            float bp = b_proj[gc];
            #pragma unroll
            for (int r = 0; r < 4; ++r) {
                int gr = mtile * 128 + wr * 64 + mi * 16 + l4 * 4 + r;
                out[(size_t)gr * 768 + gc] = acc[mi][ni][r] + bp;
            }
        }
    }
}

// ---------------- fused attention: kv = k^T v, z, out = z*(q@kv) + dwconv(v) ----------------
// One block per (b,h). Everything through LDS: no kvg/zg global round-trip, q/v read once.
// kv_l XOR-swizzled on 16B slots (slot ^= d&7) so PV b-frag reads are 2-way (free);
// conv reads v_t (stride 232 f16 -> 2-way free); q_l stride 72 f16 -> 2-way free.
__global__ __launch_bounds__(512) void attn_fused_kernel(
    const _Float16* __restrict__ qh, const _Float16* __restrict__ kh,
    const _Float16* __restrict__ vh,
    const float* __restrict__ dwc_w, const float* __restrict__ dwc_b,
    _Float16* __restrict__ fused) {
    __shared__ _Float16 k_t[64 * 232];
    __shared__ _Float16 v_t[64 * 232];
    __shared__ _Float16 q_l[208 * 72];
    __shared__ _Float16 kv_l[64 * 64];
    __shared__ float ksum_p[8 * 64];
    __shared__ float ksum[64];
    __shared__ float zz[196];

    int bh = blockIdx.x;
    int bb = bh / 12, hh = bh - bb * 12;
    int tid = threadIdx.x;
    int lane = tid & 63, wave = tid >> 6;
    int l15 = lane & 15, l4 = lane >> 4;
    size_t base = (size_t)bh * 12544;

    // zero pad: k_t/v_t cols [196,232), q_l rows [196,208)
    for (int idx = tid; idx < 1152; idx += 512) {
        int c = idx / 18, u = idx - c * 18;
        ((unsigned int*)(k_t + c * 232 + 196))[u] = 0u;
        ((unsigned int*)(v_t + c * 232 + 196))[u] = 0u;
    }
    for (int i = tid; i < 432; i += 512) ((unsigned int*)(q_l + 196 * 72))[i] = 0u;

    // load q (natural) + load/transpose k, v
    for (int j = tid; j < 3136; j += 512) {
        int e = j * 4, n = e >> 6, c = e & 63;
        half4_t kq = *(const half4_t*)(kh + base + e);
        half4_t vq = *(const half4_t*)(vh + base + e);
        *(half4_t*)(q_l + n * 72 + c) = *(const half4_t*)(qh + base + e);
        k_t[(c + 0) * 232 + n] = kq[0]; k_t[(c + 1) * 232 + n] = kq[1];
        k_t[(c + 2) * 232 + n] = kq[2]; k_t[(c + 3) * 232 + n] = kq[3];
        v_t[(c + 0) * 232 + n] = vq[0]; v_t[(c + 1) * 232 + n] = vq[1];
        v_t[(c + 2) * 232 + n] = vq[2]; v_t[(c + 3) * 232 + n] = vq[3];
    }
    __syncthreads();

    // kv = k^T v (64x64): wave -> (ct, dt0), (ct, dt0+1); store to kv_l[d][c] swizzled
    {
        int ct = wave >> 1, dt0 = (wave & 1) * 2;
        f32x4 acc0 = {0.f, 0.f, 0.f, 0.f}, acc1 = {0.f, 0.f, 0.f, 0.f};
        #pragma unroll
        for (int ks = 0; ks < 7; ++ks) {
            half8_t a  = *(const half8_t*)(k_t + (ct * 16 + l15) * 232 + ks * 32 + l4 * 8);
            half8_t b0 = *(const half8_t*)(v_t + (dt0 * 16 + l15) * 232 + ks * 32 + l4 * 8);
            half8_t b1 = *(const half8_t*)(v_t + (dt0 * 16 + 16 + l15) * 232 + ks * 32 + l4 * 8);
            acc0 = MFMA16(a, b0, acc0);
            acc1 = MFMA16(a, b1, acc1);
        }
        half4_t h0, h1;
        #pragma unroll
        for (int r = 0; r < 4; ++r) { h0[r] = (_Float16)acc0[r]; h1[r] = (_Float16)acc1[r]; }
        // kv_l[d][e] at slot (e>>3)^(d&7), sub e&7;  e = ct*16 + l4*4
        int slot = ct * 2 + (l4 >> 1), sub = (l4 & 1) * 4;
        int d0 = dt0 * 16 + l15, d1 = d0 + 16;
        *(half4_t*)(kv_l + d0 * 64 + (((slot ^ (d0 & 7)) << 3) + sub)) = h0;
        *(half4_t*)(kv_l + d1 * 64 + (((slot ^ (d1 & 7)) << 3) + sub)) = h1;
    }
    // ksum partials
    {
        int n0 = wave * 25;
        int n1 = (n0 + 25 < 196) ? (n0 + 25) : 196;
        float s = 0.f;
        for (int n = n0; n < n1; ++n) s += (float)k_t[lane * 232 + n];
        ksum_p[wave * 64 + lane] = s;
    }
    __syncthreads();
    if (tid < 64) {
        float s = 0.f;
        #pragma unroll
        for (int w = 0; w < 8; ++w) s += ksum_p[w * 64 + tid];
        ksum[tid] = s;
    }
    __syncthreads();
    if (tid < 196) {
        float s = 0.f;
        #pragma unroll
        for (int c = 0; c < 64; ++c) s += (float)q_l[tid * 72 + c] * ksum[c];
        zz[tid] = 1.0f / (s + 1e-6f);
    }
    __syncthreads();

    // PV + depthwise conv
    for (int t = wave; t < 52; t += 8) {
        int mt = t >> 2, dt = t & 3;
        int d = dt * 16 + l15;
        f32x4 acc = {0.f, 0.f, 0.f, 0.f};
        half8_t a0 = *(const half8_t*)(q_l + (mt * 16 + l15) * 72 + l4 * 8);
        half8_t a1 = *(const half8_t*)(q_l + (mt * 16 + l15) * 72 + 32 + l4 * 8);
        half8_t b0 = *(const half8_t*)(kv_l + d * 64 + ((l4 ^ (d & 7)) << 3));
        half8_t b1 = *(const half8_t*)(kv_l + d * 64 + (((l4 + 4) ^ (d & 7)) << 3));
        acc = MFMA16(a0, b0, acc);
        acc = MFMA16(a1, b1, acc);

        float bd = dwc_b[d];
        float wc[25];
        #pragma unroll
        for (int j2 = 0; j2 < 25; ++j2) wc[j2] = dwc_w[d * 25 + j2];

        #pragma unroll
        for (int r = 0; r < 4; ++r) {
            int i = mt * 16 + l4 * 4 + r;
            if (i < 196) {
                int y = i / 14, x2 = i - y * 14;
                float cacc = bd;
                #pragma unroll
                for (int ky = 0; ky < 5; ++ky) {
                    int yy = y + ky - 2;
                    bool oky = (unsigned)yy < 14u;
                    #pragma unroll
                    for (int kx = 0; kx < 5; ++kx) {
                        int xx = x2 + kx - 2;
                        if (oky && (unsigned)xx < 14u)
                            cacc += (float)v_t[d * 232 + (yy * 14 + xx)] * wc[ky * 5 + kx];
                    }
                }
                float res = acc[r] * zz[i] + cacc;
                fused[((size_t)bb * 196 + i) * 768 + hh * 64 + d] = (_Float16)res;
            }
        }
    }
}

// ---------------- launcher ----------------

extern "C" void kernel_launch(void* const* d_in, const int* in_sizes, int n_in,
                              void* d_out, int out_size, void* d_ws, size_t ws_size,
                              hipStream_t stream) {
    const float* x       = (const float*)d_in[0];
    const float* w_qkv   = (const float*)d_in[1];
    const float* pos_enc = (const float*)d_in[2];
    const float* dwc_w   = (const float*)d_in[3];
    const float* dwc_b   = (const float*)d_in[4];
    const float* w_proj  = (const float*)d_in[5];
    const float* b_proj  = (const float*)d_in[6];

    const size_t NEEDED = 340574208;
    if (ws_size < NEEDED) return;  // insufficient scratch; bail (output stays poisoned)

    char* ws = (char*)d_ws;
    _Float16* xh     = (_Float16*)(ws + 0);          // 77,070,336 B (also 'fused' later)
    _Float16* fused  = xh;
    _Float16* wqkvT  = (_Float16*)(ws + 77070336);   // 3,538,944
    _Float16* wprojT = (_Float16*)(ws + 80609280);   // 1,179,648
    _Float16* qh     = (_Float16*)(ws + 81788928);   // 77,070,336
    _Float16* kh     = (_Float16*)(ws + 158859264);  // 77,070,336
    _Float16* vh     = (_Float16*)(ws + 235929600);  // 77,070,336

    cvt_f2h_kernel<<<4096, 256, 0, stream>>>(x, xh, 9633792);
    transpose768_kernel<<<(2304 * 768 + 255) / 256, 256, 0, stream>>>(w_qkv, wqkvT, 2304);
    transpose768_kernel<<<(768 * 768 + 255) / 256, 256, 0, stream>>>(w_proj, wprojT, 768);
    gemm_qkv_kernel<<<392 * 9, 512, 0, stream>>>(xh, wqkvT, pos_enc, qh, kh, vh);
    attn_fused_kernel<<<3072, 512, 0, stream>>>(qh, kh, vh, dwc_w, dwc_b, fused);
    gemm_proj_kernel<<<392 * 3, 512, 0, stream>>>(fused, wprojT, b_proj, (float*)d_out);
}

// Round 9
// 660.230 us; speedup vs baseline: 1.2701x; 1.2701x over previous
//
#include <hip/hip_runtime.h>

typedef _Float16 half8_t __attribute__((ext_vector_type(8)));
typedef _Float16 half4_t __attribute__((ext_vector_type(4)));
typedef float f32x4 __attribute__((ext_vector_type(4)));

#define MFMA16(a, b, c) __builtin_amdgcn_mfma_f32_16x16x32_f16((a), (b), (c), 0, 0, 0)

typedef const unsigned int __attribute__((address_space(1)))* gas_ptr;
typedef unsigned int __attribute__((address_space(3)))* las_ptr;

__device__ __forceinline__ void gload16(const void* g, void* l) {
    __builtin_amdgcn_global_load_lds((gas_ptr)g, (las_ptr)l, 16, 0, 0);
}

// m204 bijective XCD swizzle: contiguous wgid chunk per XCD (works for nwg % 8 != 0)
__device__ __forceinline__ int xcd_swizzle(int bid, int nwg) {
    int xcd = bid & 7, i = bid >> 3;
    int q = nwg >> 3, r = nwg & 7;
    return (xcd < r ? xcd * (q + 1) : r * (q + 1) + (xcd - r) * q) + i;
}

// ---------------- convert / transpose ----------------

__global__ void cvt_f2h_kernel(const float* __restrict__ in, _Float16* __restrict__ out, int n4) {
    int stride = gridDim.x * blockDim.x;
    for (int i = blockIdx.x * blockDim.x + threadIdx.x; i < n4; i += stride) {
        f32x4 v = *(const f32x4*)(in + (size_t)4 * i);
        half4_t h;
        h[0] = (_Float16)v[0]; h[1] = (_Float16)v[1];
        h[2] = (_Float16)v[2]; h[3] = (_Float16)v[3];
        *(half4_t*)(out + (size_t)4 * i) = h;
    }
}

// out[j][k] = in[k][j], K fixed at 768
__global__ void transpose768_kernel(const float* __restrict__ in, _Float16* __restrict__ out, int ncols) {
    int idx = blockIdx.x * 256 + threadIdx.x;
    int total = ncols * 768;
    if (idx < total) {
        int j = idx / 768;
        int k = idx - j * 768;
        out[idx] = (_Float16)in[(size_t)k * ncols + j];
    }
}

// ---------------- GEMM core: 128x256 tile, BK=32, 8 waves, 2 blocks/CU ----------------
// (unchanged from R8 — validated, 0 LDS conflicts)

#define STG(buf, kof)                                                             \
    {                                                                             \
        _Float16* Ad = lds + (buf) * 12288 + wave * 512;                          \
        _Float16* Bd = lds + (buf) * 12288 + 4096 + wave * 512;                   \
        gload16(Arow + (kof), Ad);                                                \
        gload16(Brow + (kof), Bd);                                                \
        gload16(Brow + (kof) + 98304, Bd + 4096);                                 \
    }

__device__ __forceinline__ void run_gemm128x256(const _Float16* __restrict__ A,
                                                const _Float16* __restrict__ Bt,
                                                int mbase, int nbase,
                                                _Float16* lds,          // 24576 f16
                                                f32x4 (&acc)[4][4]) {
    const int tid = threadIdx.x;
    const int lane = tid & 63;
    const int wave = tid >> 6;
    const int wr = wave >> 2;        // 0..1  (M half, 64 rows)
    const int wc = wave & 3;         // 0..3  (N quarter, 64 cols)
    const int l15 = lane & 15;
    const int l4 = lane >> 4;
    const int rsw = ((l4 ^ ((l15 >> 1) & 3)) << 3);             // read k-slot offset
    const int ksw = (((tid & 3) ^ ((tid >> 3) & 3)) << 3);      // staging source pre-swizzle

    #pragma unroll
    for (int mi = 0; mi < 4; ++mi)
        #pragma unroll
        for (int ni = 0; ni < 4; ++ni)
            acc[mi][ni] = (f32x4){0.f, 0.f, 0.f, 0.f};

    const _Float16* Arow = A + (size_t)(mbase + (tid >> 2)) * 768 + ksw;   // rows 0..127
    const _Float16* Brow = Bt + (size_t)(nbase + (tid >> 2)) * 768 + ksw;  // rows 0..127 (+128 in STG)

    STG(0, 0)
    __syncthreads();

    #pragma unroll 2
    for (int kt = 0; kt < 24; ++kt) {
        const int buf = kt & 1;
        if (kt < 23) STG(buf ^ 1, (kt + 1) * 32)

        const _Float16* Ac = lds + buf * 12288;
        const _Float16* Bc = Ac + 4096;
        half8_t a[4], b[4];
        #pragma unroll
        for (int mi = 0; mi < 4; ++mi)
            a[mi] = *(const half8_t*)(Ac + (wr * 64 + mi * 16 + l15) * 32 + rsw);
        #pragma unroll
        for (int ni = 0; ni < 4; ++ni)
            b[ni] = *(const half8_t*)(Bc + (wc * 64 + ni * 16 + l15) * 32 + rsw);
        #pragma unroll
        for (int mi = 0; mi < 4; ++mi)
            #pragma unroll
            for (int ni = 0; ni < 4; ++ni)
                acc[mi][ni] = MFMA16(a[mi], b[ni], acc[mi][ni]);
        __syncthreads();
    }
}

// GEMM1: qkv = x @ w_qkv. Epilogue: q -> qh natural [bh][196][64] (relu);
// k -> khT [bh][64][196] (pos_enc+relu, half4 contiguous-n stores);
// v -> vhT [bh][64][196] (half4 stores). 4-aligned n-quads never span a batch
// boundary (196 % 4 == 0), so half4 writes are always within one (b,h) row.
__global__ __launch_bounds__(512, 4) void gemm_qkv_kernel(
    const _Float16* __restrict__ xh, const _Float16* __restrict__ wqkvT,
    const float* __restrict__ pos_enc,
    _Float16* __restrict__ qh, _Float16* __restrict__ khT, _Float16* __restrict__ vhT) {
    __shared__ _Float16 lds[24576];
    int wgid = xcd_swizzle(blockIdx.x, 392 * 9);
    int mtile = wgid / 9, ntile = wgid - mtile * 9;
    f32x4 acc[4][4];
    run_gemm128x256(xh, wqkvT, mtile * 128, ntile * 256, lds, acc);

    const int tid = threadIdx.x;
    const int lane = tid & 63;
    const int wave = tid >> 6;
    const int wr = wave >> 2;
    const int wc = wave & 3;
    const int l15 = lane & 15;
    const int l4 = lane >> 4;

    // 768 = 3*256: all 256 columns of this block live in one q/k/v segment
    const int s = ntile / 3;
    const int cb = (ntile - s * 3) * 256 + wc * 64;

    if (s == 0) {
        #pragma unroll
        for (int mi = 0; mi < 4; ++mi) {
            #pragma unroll
            for (int ni = 0; ni < 4; ++ni) {
                int c = cb + ni * 16 + l15;
                int h = c >> 6, d = c & 63;
                #pragma unroll
                for (int r = 0; r < 4; ++r) {
                    int gr = mtile * 128 + wr * 64 + mi * 16 + l4 * 4 + r;
                    int b = gr / 196;
                    int n = gr - b * 196;
                    qh[((size_t)(b * 12 + h) * 196 + n) * 64 + d] =
                        (_Float16)fmaxf(acc[mi][ni][r], 0.f);
                }
            }
        }
    } else {
        _Float16* dstT = (s == 1) ? khT : vhT;
        #pragma unroll
        for (int mi = 0; mi < 4; ++mi) {
            int gr0 = mtile * 128 + wr * 64 + mi * 16 + l4 * 4;
            int b = gr0 / 196, n0 = gr0 - b * 196;
            #pragma unroll
            for (int ni = 0; ni < 4; ++ni) {
                int c = cb + ni * 16 + l15;
                int h = c >> 6, d = c & 63;
                half4_t w;
                #pragma unroll
                for (int r = 0; r < 4; ++r) {
                    float v = acc[mi][ni][r];
                    if (s == 1) { v += pos_enc[(n0 + r) * 768 + c]; v = fmaxf(v, 0.f); }
                    w[r] = (_Float16)v;
                }
                *(half4_t*)(dstT + ((size_t)(b * 12 + h) * 64 + d) * 196 + n0) = w;
            }
        }
    }
}

// GEMM2: out = fused @ w_proj + b_proj (f32 out)
__global__ __launch_bounds__(512, 4) void gemm_proj_kernel(
    const _Float16* __restrict__ fused, const _Float16* __restrict__ wprojT,
    const float* __restrict__ b_proj, float* __restrict__ out) {
    __shared__ _Float16 lds[24576];
    int wgid = xcd_swizzle(blockIdx.x, 392 * 3);
    int mtile = wgid / 3, ntile = wgid - mtile * 3;
    f32x4 acc[4][4];
    run_gemm128x256(fused, wprojT, mtile * 128, ntile * 256, lds, acc);

    const int tid = threadIdx.x;
    const int lane = tid & 63;
    const int wave = tid >> 6;
    const int wr = wave >> 2;
    const int wc = wave & 3;
    const int l15 = lane & 15;
    const int l4 = lane >> 4;

    #pragma unroll
    for (int mi = 0; mi < 4; ++mi) {
        #pragma unroll
        for (int ni = 0; ni < 4; ++ni) {
            int gc = ntile * 256 + wc * 64 + ni * 16 + l15;
            float bp = b_proj[gc];
            #pragma unroll
            for (int r = 0; r < 4; ++r) {
                int gr = mtile * 128 + wr * 64 + mi * 16 + l4 * 4 + r;
                out[(size_t)gr * 768 + gc] = acc[mi][ni][r] + bp;
            }
        }
    }
}

// ---------------- fused attention v2: no transpose, 2 blocks/CU ----------------
// khT/vhT arrive pre-transposed [bh][64][196] -> LDS staging is contiguous half8
// row copies (conflict-free). q read directly from global (PV A-frags + z dot).
// LDS = 70.7 KB -> 2 blocks/CU hides the serial phase chain.
__global__ __launch_bounds__(512, 4) void attn_fused_kernel(
    const _Float16* __restrict__ qh, const _Float16* __restrict__ khT,
    const _Float16* __restrict__ vhT,
    const float* __restrict__ dwc_w, const float* __restrict__ dwc_b,
    _Float16* __restrict__ fused) {
    __shared__ _Float16 k_t[64 * 232];
    __shared__ _Float16 v_t[64 * 232];
    __shared__ _Float16 kv_l[64 * 64];
    __shared__ float ksum_p[512];
    __shared__ float ksum[64];
    __shared__ float zz[196];

    int bh = blockIdx.x;
    int bb = bh / 12, hh = bh - bb * 12;
    int tid = threadIdx.x;
    int lane = tid & 63, wave = tid >> 6;
    int l15 = lane & 15, l4 = lane >> 4;
    size_t base = (size_t)bh * 12544;

    // stage khT/vhT rows -> LDS [64][232] (rows 196 els + zero pad to 232)
    for (int s = tid; s < 1856; s += 512) {
        int c = s / 29, g = s - c * 29;
        half8_t kk = {0, 0, 0, 0, 0, 0, 0, 0}, vv = {0, 0, 0, 0, 0, 0, 0, 0};
        const _Float16* kp = khT + base + c * 196 + g * 8;
        const _Float16* vp = vhT + base + c * 196 + g * 8;
        if (g < 24) {
            kk = *(const half8_t*)kp; vv = *(const half8_t*)vp;
        } else if (g == 24) {
            half4_t k4 = *(const half4_t*)kp, v4 = *(const half4_t*)vp;
            kk[0] = k4[0]; kk[1] = k4[1]; kk[2] = k4[2]; kk[3] = k4[3];
            vv[0] = v4[0]; vv[1] = v4[1]; vv[2] = v4[2]; vv[3] = v4[3];
        }
        *(half8_t*)(k_t + c * 232 + g * 8) = kk;
        *(half8_t*)(v_t + c * 232 + g * 8) = vv;
    }
    __syncthreads();

    // kv = k^T v (64x64): wave -> (ct, dt0), (ct, dt0+1); store kv_l[d][c] swizzled
    {
        int ct = wave >> 1, dt0 = (wave & 1) * 2;
        f32x4 acc0 = {0.f, 0.f, 0.f, 0.f}, acc1 = {0.f, 0.f, 0.f, 0.f};
        #pragma unroll
        for (int ks = 0; ks < 7; ++ks) {
            half8_t a  = *(const half8_t*)(k_t + (ct * 16 + l15) * 232 + ks * 32 + l4 * 8);
            half8_t b0 = *(const half8_t*)(v_t + (dt0 * 16 + l15) * 232 + ks * 32 + l4 * 8);
            half8_t b1 = *(const half8_t*)(v_t + (dt0 * 16 + 16 + l15) * 232 + ks * 32 + l4 * 8);
            acc0 = MFMA16(a, b0, acc0);
            acc1 = MFMA16(a, b1, acc1);
        }
        half4_t h0, h1;
        #pragma unroll
        for (int r = 0; r < 4; ++r) { h0[r] = (_Float16)acc0[r]; h1[r] = (_Float16)acc1[r]; }
        // kv_l[d][e] at slot (e>>3)^(d&7), sub e&7;  e = ct*16 + l4*4
        int slot = ct * 2 + (l4 >> 1), sub = (l4 & 1) * 4;
        int d0 = dt0 * 16 + l15, d1 = d0 + 16;
        *(half4_t*)(kv_l + d0 * 64 + (((slot ^ (d0 & 7)) << 3) + sub)) = h0;
        *(half4_t*)(kv_l + d1 * 64 + (((slot ^ (d1 & 7)) << 3) + sub)) = h1;
    }
    // ksum partials: thread (wave,lane) sums k_t[lane][wave*25 .. +25)
    {
        int n0 = wave * 25;
        int n1 = (n0 + 25 < 196) ? (n0 + 25) : 196;
        float s = 0.f;
        for (int n = n0; n < n1; ++n) s += (float)k_t[lane * 232 + n];
        ksum_p[wave * 64 + lane] = s;
    }
    __syncthreads();
    if (tid < 64) {
        float s = 0.f;
        #pragma unroll
        for (int w = 0; w < 8; ++w) s += ksum_p[w * 64 + tid];
        ksum[tid] = s;
    }
    __syncthreads();
    if (tid < 196) {
        const _Float16* qrow = qh + base + tid * 64;
        float s = 0.f;
        #pragma unroll
        for (int c8 = 0; c8 < 8; ++c8) {
            half8_t qv = *(const half8_t*)(qrow + c8 * 8);
            #pragma unroll
            for (int j = 0; j < 8; ++j) s += (float)qv[j] * ksum[c8 * 8 + j];
        }
        zz[tid] = 1.0f / (s + 1e-6f);
    }
    __syncthreads();

    // PV + depthwise conv; q A-frags straight from global (rows >=196 feed only
    // discarded C-rows; tail block's overread lands in khT allocation - safe)
    for (int t = wave; t < 52; t += 8) {
        int mt = t >> 2, dt = t & 3;
        int d = dt * 16 + l15;
        f32x4 acc = {0.f, 0.f, 0.f, 0.f};
        const _Float16* qrow = qh + base + (mt * 16 + l15) * 64;
        half8_t a0 = *(const half8_t*)(qrow + l4 * 8);
        half8_t a1 = *(const half8_t*)(qrow + 32 + l4 * 8);
        half8_t b0 = *(const half8_t*)(kv_l + d * 64 + ((l4 ^ (d & 7)) << 3));
        half8_t b1 = *(const half8_t*)(kv_l + d * 64 + (((l4 + 4) ^ (d & 7)) << 3));
        acc = MFMA16(a0, b0, acc);
        acc = MFMA16(a1, b1, acc);

        float bd = dwc_b[d];
        float wc[25];
        #pragma unroll
        for (int j2 = 0; j2 < 25; ++j2) wc[j2] = dwc_w[d * 25 + j2];

        #pragma unroll
        for (int r = 0; r < 4; ++r) {
            int i = mt * 16 + l4 * 4 + r;
            if (i < 196) {
                int y = i / 14, x2 = i - y * 14;
                float cacc = bd;
                #pragma unroll
                for (int ky = 0; ky < 5; ++ky) {
                    int yy = y + ky - 2;
                    bool oky = (unsigned)yy < 14u;
                    #pragma unroll
                    for (int kx = 0; kx < 5; ++kx) {
                        int xx = x2 + kx - 2;
                        if (oky && (unsigned)xx < 14u)
                            cacc += (float)v_t[d * 232 + (yy * 14 + xx)] * wc[ky * 5 + kx];
                    }
                }
                float res = acc[r] * zz[i] + cacc;
                fused[((size_t)bb * 196 + i) * 768 + hh * 64 + d] = (_Float16)res;
            }
        }
    }
}

// ---------------- launcher ----------------

extern "C" void kernel_launch(void* const* d_in, const int* in_sizes, int n_in,
                              void* d_out, int out_size, void* d_ws, size_t ws_size,
                              hipStream_t stream) {
    const float* x       = (const float*)d_in[0];
    const float* w_qkv   = (const float*)d_in[1];
    const float* pos_enc = (const float*)d_in[2];
    const float* dwc_w   = (const float*)d_in[3];
    const float* dwc_b   = (const float*)d_in[4];
    const float* w_proj  = (const float*)d_in[5];
    const float* b_proj  = (const float*)d_in[6];

    const size_t NEEDED = 340574208;
    if (ws_size < NEEDED) return;  // insufficient scratch; bail (output stays poisoned)

    char* ws = (char*)d_ws;
    _Float16* xh     = (_Float16*)(ws + 0);          // 77,070,336 B (also 'fused' later)
    _Float16* fused  = xh;
    _Float16* wqkvT  = (_Float16*)(ws + 77070336);   // 3,538,944
    _Float16* wprojT = (_Float16*)(ws + 80609280);   // 1,179,648
    _Float16* qh     = (_Float16*)(ws + 81788928);   // 77,070,336  natural [bh][196][64]
    _Float16* khT    = (_Float16*)(ws + 158859264);  // 77,070,336  transposed [bh][64][196]
    _Float16* vhT    = (_Float16*)(ws + 235929600);  // 77,070,336  transposed [bh][64][196]

    cvt_f2h_kernel<<<4096, 256, 0, stream>>>(x, xh, 9633792);
    transpose768_kernel<<<(2304 * 768 + 255) / 256, 256, 0, stream>>>(w_qkv, wqkvT, 2304);
    transpose768_kernel<<<(768 * 768 + 255) / 256, 256, 0, stream>>>(w_proj, wprojT, 768);
    gemm_qkv_kernel<<<392 * 9, 512, 0, stream>>>(xh, wqkvT, pos_enc, qh, khT, vhT);
    attn_fused_kernel<<<3072, 512, 0, stream>>>(qh, khT, vhT, dwc_w, dwc_b, fused);
    gemm_proj_kernel<<<392 * 3, 512, 0, stream>>>(fused, wprojT, b_proj, (float*)d_out);
}